// Round 8
// baseline (119.194 us; speedup 1.0000x reference)
//
#include <hip/hip_runtime.h>
#include <hip/hip_bf16.h>
#include <stdint.h>

// out_re[b,i] = sum_j T_re[j,i]*p[i,j] - T_im[j,i]*q[i,j]   (d_out = Re only)
//   T_re = R*P^T + M*Q^T ; T_im = M*P^T - R*Q^T  via 16x16x32 bf16 MFMA.
// Round-8: NO K staging in the main kernel. A pre-pass converts K to bf16 in
// MFMA-fragment order in d_ws (P / Q / negated-Q streams; 96KB, L2-broadcast).
// Main kernel: LDS 64KB -> 4KB (partials only), no staging barrier ->
// occupancy cap 2 -> 4 blocks/CU; latency hidden by TLP instead of the
// ILP the compiler keeps refusing (VGPR stuck at 64-72, rounds 6-7).

typedef __attribute__((ext_vector_type(8))) __bf16 bf16x8;
typedef __attribute__((ext_vector_type(4))) float f32x4;
typedef __attribute__((ext_vector_type(4))) unsigned int u32x4;

#define EDIM 128
// d_ws layout (bf16 elements): P[0,16384) Q[16384,32768) Qn[32768,49152)
#define FRAG_ELEMS 16384

static __device__ inline bf16x8 neg8(bf16x8 v) {
    u32x4 u = __builtin_bit_cast(u32x4, v);
    u ^= (u32x4){0x80008000u, 0x80008000u, 0x80008000u, 0x80008000u};
    return __builtin_bit_cast(bf16x8, u);
}

// ---- pre-pass: K (f32 interleaved p,q) -> bf16 fragment-ordered streams ----
// frag index f = nT*4+u (nT: i-tile 0..7, u: k-block 0..3); within f, lane
// (li=lane&15, s=lane>>4) holds K[i=nT*16+li][l=u*32+s*8 .. +8).
__global__ void kprep_kernel(const float* __restrict__ Kern, __bf16* __restrict__ kf)
{
    int id = blockIdx.x * 256 + threadIdx.x;    // 0..2047
    int f    = id >> 6;                         // 0..31
    int lane = id & 63;
    int nT = f >> 2, u = f & 3;
    int li = lane & 15, s = lane >> 4;
    int i  = nT * 16 + li;
    int l0 = u * 32 + s * 8;
    const float* g = Kern + (((size_t)i * EDIM + l0) << 1);
    bf16x8 p, q;
#pragma unroll
    for (int e = 0; e < 8; ++e) {
        p[e] = (__bf16)g[2 * e];
        q[e] = (__bf16)g[2 * e + 1];
    }
    bf16x8* P  = (bf16x8*)kf;
    bf16x8* Q  = (bf16x8*)(kf + FRAG_ELEMS);
    bf16x8* Qn = (bf16x8*)(kf + 2 * FRAG_ELEMS);
    P[id]  = p;
    Q[id]  = q;
    Qn[id] = neg8(q);
}

__global__ __launch_bounds__(512, 4) void qmeas_kernel(
    const float* __restrict__ R, const float* __restrict__ M,
    const float* __restrict__ Kern, const __bf16* __restrict__ kf,
    float* __restrict__ out, int nout)
{
    __shared__ float part[8 * EDIM];   // 4KB

    const int t    = threadIdx.x;
    const int lane = t & 63;
    const int w    = t >> 6;       // wave 0..7
    const int li   = lane & 15;
    const int s    = lane >> 4;    // 0..3
    const int b    = blockIdx.x;

    // ---- load this wave's X rows and convert to bf16 fragments ----
    const int    jj = (w << 4) + li;              // this lane's A-row (j)
    const float* Rp = R + (size_t)b * (EDIM * EDIM) + (size_t)jj * EDIM + s * 8;
    const float* Mp = M + (size_t)b * (EDIM * EDIM) + (size_t)jj * EDIM + s * 8;

    bf16x8 ra[4], ma[4];
#pragma unroll
    for (int u = 0; u < 4; ++u) {
        f32x4 r0 = *(const f32x4*)(Rp + u * 32);
        f32x4 r1 = *(const f32x4*)(Rp + u * 32 + 4);
        f32x4 m0 = *(const f32x4*)(Mp + u * 32);
        f32x4 m1 = *(const f32x4*)(Mp + u * 32 + 4);
#pragma unroll
        for (int e = 0; e < 4; ++e) {
            ra[u][e]     = (__bf16)r0[e];
            ra[u][4 + e] = (__bf16)r1[e];
            ma[u][e]     = (__bf16)m0[e];
            ma[u][4 + e] = (__bf16)m1[e];
        }
    }

    // ---- main: nT outer (live acc = 8 regs); B-fragments from L2 streams ----
    // D layout: col i = lane&15, row j = jrow0 + reg, jrow0 = w*16 + s*4
    const int jrow0 = (w << 4) + (s << 2);
    const bf16x8* Pf  = (const bf16x8*)kf;
    const bf16x8* Qf  = (const bf16x8*)(kf + FRAG_ELEMS);
    const bf16x8* Qnf = (const bf16x8*)(kf + 2 * FRAG_ELEMS);
    float re8[8];
#pragma unroll
    for (int nT = 0; nT < 8; ++nT) {
        const int i = (nT << 4) + li;
        const float* kp = Kern + (((size_t)i * EDIM + jrow0) << 1);
        f32x4 k0 = *(const f32x4*)(kp);       // p0 q0 p1 q1
        f32x4 k1 = *(const f32x4*)(kp + 4);   // p2 q2 p3 q3
        f32x4 are = (f32x4){0.f, 0.f, 0.f, 0.f};
        f32x4 aim = (f32x4){0.f, 0.f, 0.f, 0.f};
#pragma unroll
        for (int u = 0; u < 4; ++u) {
            const int fi = ((nT << 2) + u) * 64 + lane;   // coalesced 1KB/wave
            bf16x8 pB = Pf[fi];
            bf16x8 qB = Qf[fi];
            bf16x8 qN = Qnf[fi];
            are = __builtin_amdgcn_mfma_f32_16x16x32_bf16(ra[u], pB, are, 0, 0, 0);
            are = __builtin_amdgcn_mfma_f32_16x16x32_bf16(ma[u], qB, are, 0, 0, 0);
            aim = __builtin_amdgcn_mfma_f32_16x16x32_bf16(ma[u], pB, aim, 0, 0, 0);
            aim = __builtin_amdgcn_mfma_f32_16x16x32_bf16(ra[u], qN, aim, 0, 0, 0);
        }
        float re = are[0] * k0[0] - aim[0] * k0[1]
                 + are[1] * k0[2] - aim[1] * k0[3]
                 + are[2] * k1[0] - aim[2] * k1[1]
                 + are[3] * k1[2] - aim[3] * k1[3];
        re += __shfl_xor(re, 16);
        re += __shfl_xor(re, 32);
        re8[nT] = re;
    }

    // ---- cross-wave partial reduce (4KB LDS) + store (Re only) ----
    if (s == 0) {
#pragma unroll
        for (int nT = 0; nT < 8; ++nT) {
            part[w * EDIM + (nT << 4) + li] = re8[nT];
        }
    }
    __syncthreads();
    if (t < EDIM) {
        float sum = part[t];
#pragma unroll
        for (int ww = 1; ww < 8; ++ww) sum += part[ww * EDIM + t];
        int oi = b * EDIM + t;
        if (oi < nout) out[oi] = sum;
    }
}

extern "C" void kernel_launch(void* const* d_in, const int* in_sizes, int n_in,
                              void* d_out, int out_size, void* d_ws, size_t ws_size,
                              hipStream_t stream) {
    const float* R    = (const float*)d_in[0];
    const float* M    = (const float*)d_in[1];
    const float* Kern = (const float*)d_in[2];
    float*       out  = (float*)d_out;
    __bf16*      kf   = (__bf16*)d_ws;          // needs 96KB of ws
    const int    B    = in_sizes[0] / (EDIM * EDIM);   // 2048

    kprep_kernel<<<8, 256, 0, stream>>>(Kern, kf);
    qmeas_kernel<<<B, 512, 0, stream>>>(R, M, Kern, kf, out, out_size);
}

// Round 9
// 81.692 us; speedup vs baseline: 1.4591x; 1.4591x over previous
//
#include <hip/hip_runtime.h>
#include <hip/hip_bf16.h>
#include <stdint.h>

// out_re[b,i] = sum_{j,l} Re{ x[b,j,l] * k[i,j] * conj(k[i,l]) }
// T[i,j] = sum_l K[i,l]·X[j,l] pieces via MFMA with A = K-frags (regs,
// persistent), B = X-frags (LDS, staged by global_load_lds DMA).
//   T_re = P·R + Q·M ; T_im = P·M + Q·(-R)
// Epilogue: out_re[b,i] = sum_j T_re·p[i,j] - T_im·q[i,j]  (f32 weights).
// Round-9: X staged via global_load_lds (async DMA — bypasses the register
// allocator that kept serializing VGPR loads, rounds 4-8). 8 phases/batch
// (j-half x l-chunk), 16KB tiles double-buffered, source-side XOR pre-swizzle
// so ds_read_b128 B-frags are conflict-free. Wave owns an i-tile; j reduced
// in-wave -> no partials LDS, no tail barrier.

typedef __attribute__((ext_vector_type(8))) __bf16 bf16x8;
typedef __attribute__((ext_vector_type(4))) float f32x4;
typedef __attribute__((ext_vector_type(4))) unsigned int u32x4;

#define EDIM 128
#define FRAG_ELEMS 16384   // d_ws bf16 elems: P[0,16384) Q[16384,32768)

static __device__ inline bf16x8 neg8(bf16x8 v) {
    u32x4 u = __builtin_bit_cast(u32x4, v);
    u ^= (u32x4){0x80008000u, 0x80008000u, 0x80008000u, 0x80008000u};
    return __builtin_bit_cast(bf16x8, u);
}

// ---- pre-pass: K (f32 interleaved p,q) -> bf16 fragment streams P, Q ----
// frag f = nT*4+u; lane (li,s) holds K[nT*16+li][u*32+s*8 .. +8)
__global__ void kprep_kernel(const float* __restrict__ Kern, __bf16* __restrict__ kf)
{
    int id = blockIdx.x * 256 + threadIdx.x;    // 0..2047
    int f    = id >> 6;
    int lane = id & 63;
    int nT = f >> 2, u = f & 3;
    int li = lane & 15, s = lane >> 4;
    int i  = nT * 16 + li;
    int l0 = u * 32 + s * 8;
    const float* g = Kern + (((size_t)i * EDIM + l0) << 1);
    bf16x8 p, q;
#pragma unroll
    for (int e = 0; e < 8; ++e) {
        p[e] = (__bf16)g[2 * e];
        q[e] = (__bf16)g[2 * e + 1];
    }
    ((bf16x8*)kf)[id]               = p;
    ((bf16x8*)(kf + FRAG_ELEMS))[id] = q;
}

#define ASG(p) (__attribute__((address_space(1))) const void*)(p)
#define ASL(p) (__attribute__((address_space(3))) void*)(p)

__global__ __launch_bounds__(512, 4) void qmeas_kernel(
    const float* __restrict__ R, const float* __restrict__ M,
    const float* __restrict__ Kern, const __bf16* __restrict__ kf,
    float* __restrict__ out, int nout)
{
    // [0,16K) buf0 (R 8K | M 8K), [16K,32K) buf1
    __shared__ __align__(16) unsigned char smem[32768];

    const int t    = threadIdx.x;
    const int lane = t & 63;
    const int w    = t >> 6;       // wave 0..7 = i-tile
    const int li   = lane & 15;
    const int s    = lane >> 4;    // 0..3
    const int b    = blockIdx.x;

    // ---- persistent A-fragments: K rows i0..i0+16 (32 VGPRs) ----
    const bf16x8* Pf = (const bf16x8*)kf;
    const bf16x8* Qf = (const bf16x8*)(kf + FRAG_ELEMS);
    bf16x8 pa[4], qa[4];
#pragma unroll
    for (int u = 0; u < 4; ++u) {
        pa[u] = Pf[((w << 2) | u) * 64 + lane];
        qa[u] = Qf[((w << 2) | u) * 64 + lane];
    }

    // ---- staging geometry ----
    const size_t xb   = (size_t)b * (EDIM * EDIM);
    const int    rl   = lane >> 3;                       // 0..7 row in wave's group
    const int    colp = ((lane & 7) ^ rl) << 2;          // pre-swizzled col (floats)
    const int    sgrow = w * 8 + rl;                     // row within 64-row tile

    // stage tile (jh,u) into buffer `buf`: R 8KB then M 8KB, 2 DMA issues/wave
#define STAGE(buf, jh, u)                                                        \
    do {                                                                         \
        const float* gR_ = R + xb + (size_t)((jh) * 64 + sgrow) * EDIM           \
                             + (u) * 32 + colp;                                  \
        const float* gM_ = M + xb + (size_t)((jh) * 64 + sgrow) * EDIM           \
                             + (u) * 32 + colp;                                  \
        unsigned char* dR_ = smem + (buf) * 16384 + w * 1024;                    \
        __builtin_amdgcn_global_load_lds(ASG(gR_), ASL(dR_), 16, 0, 0);          \
        __builtin_amdgcn_global_load_lds(ASG(gM_), ASL(dR_ + 8192), 16, 0, 0);   \
    } while (0)

    STAGE(0, 0, 0);
    __syncthreads();

    f32x4 are[4], aim[4];
#pragma unroll
    for (int n = 0; n < 4; ++n) {
        are[n] = (f32x4){0.f, 0.f, 0.f, 0.f};
        aim[n] = (f32x4){0.f, 0.f, 0.f, 0.f};
    }
    float reS[4] = {0.f, 0.f, 0.f, 0.f};
    const int    i0 = w << 4;
    const float2* K2 = (const float2*)Kern;
    const int    swz = (li & 7) << 4;

#pragma unroll
    for (int p = 0; p < 8; ++p) {
        const int jh  = p >> 2;
        const int u   = p & 3;
        const int buf = p & 1;

        if (p < 7) STAGE((p + 1) & 1, (p + 1) >> 2, (p + 1) & 3);

        // ---- compute from buf: 4 j-tiles x 4 MFMA ----
        const unsigned char* base = smem + buf * 16384;
#pragma unroll
        for (int jt = 0; jt < 4; ++jt) {
            const int row = (jt << 4) + li;
            const int a0  = row * 128 + ((s * 32) ^ swz);
            const int a1  = row * 128 + ((s * 32 + 16) ^ swz);
            f32x4 r0 = *(const f32x4*)(base + a0);
            f32x4 r1 = *(const f32x4*)(base + a1);
            f32x4 m0 = *(const f32x4*)(base + 8192 + a0);
            f32x4 m1 = *(const f32x4*)(base + 8192 + a1);
            bf16x8 xr, xm;
#pragma unroll
            for (int e = 0; e < 4; ++e) {
                xr[e]     = (__bf16)r0[e];
                xr[4 + e] = (__bf16)r1[e];
                xm[e]     = (__bf16)m0[e];
                xm[4 + e] = (__bf16)m1[e];
            }
            bf16x8 xrn = neg8(xr);
            are[jt] = __builtin_amdgcn_mfma_f32_16x16x32_bf16(pa[u], xr,  are[jt], 0, 0, 0);
            are[jt] = __builtin_amdgcn_mfma_f32_16x16x32_bf16(qa[u], xm,  are[jt], 0, 0, 0);
            aim[jt] = __builtin_amdgcn_mfma_f32_16x16x32_bf16(pa[u], xm,  aim[jt], 0, 0, 0);
            aim[jt] = __builtin_amdgcn_mfma_f32_16x16x32_bf16(qa[u], xrn, aim[jt], 0, 0, 0);
        }

        // ---- per-j-half epilogue: weight by k[i,j] (f32), fold into reS ----
        if (u == 3) {
#pragma unroll
            for (int jt = 0; jt < 4; ++jt) {
                const int j = jh * 64 + (jt << 4) + li;
#pragma unroll
                for (int r = 0; r < 4; ++r) {
                    float2 kv = K2[(size_t)(i0 + (s << 2) + r) * EDIM + j];
                    reS[r] += are[jt][r] * kv.x - aim[jt][r] * kv.y;
                }
                are[jt] = (f32x4){0.f, 0.f, 0.f, 0.f};
                aim[jt] = (f32x4){0.f, 0.f, 0.f, 0.f};
            }
        }

        if (p < 7) __syncthreads();
    }

    // ---- reduce over li (16 lanes) and store: wave owns i0..i0+16 ----
#pragma unroll
    for (int r = 0; r < 4; ++r) {
        reS[r] += __shfl_xor(reS[r], 1);
        reS[r] += __shfl_xor(reS[r], 2);
        reS[r] += __shfl_xor(reS[r], 4);
        reS[r] += __shfl_xor(reS[r], 8);
    }
    if (li == 0) {
#pragma unroll
        for (int r = 0; r < 4; ++r) {
            int oi = b * EDIM + i0 + (s << 2) + r;
            if (oi < nout) out[oi] = reS[r];
        }
    }
}

extern "C" void kernel_launch(void* const* d_in, const int* in_sizes, int n_in,
                              void* d_out, int out_size, void* d_ws, size_t ws_size,
                              hipStream_t stream) {
    const float* R    = (const float*)d_in[0];
    const float* M    = (const float*)d_in[1];
    const float* Kern = (const float*)d_in[2];
    float*       out  = (float*)d_out;
    __bf16*      kf   = (__bf16*)d_ws;          // needs 64KB of ws
    const int    B    = in_sizes[0] / (EDIM * EDIM);   // 2048

    kprep_kernel<<<8, 256, 0, stream>>>(Kern, kf);
    qmeas_kernel<<<B, 512, 0, stream>>>(R, M, Kern, kf, out, out_size);
}